// Round 11
// baseline (1823.645 us; speedup 1.0000x reference)
//
#include <hip/hip_runtime.h>
#include <cstdint>
#include <cstddef>

// SNN_53618371723788: 2-layer SLSTM, B=65536, T=24, H=64, fp32.
// Pass 1: layer-1 recurrence, emits spike bitmasks + final mem1 to d_ws.
// Pass 2: layer-2 recurrence (sparse ih via spike masks) + extra step + Wout.
//
// R11: 4-deep sparse-read pipeline. R10 latency model: each batch's sparse
// bit-chain was serially ds_read-latency-bound (~120 cyc/bit, 2-deep hid
// ~20); 8 independent while-loops can't be compiler-interleaved (dynamic
// trip counts). ~15 bits x 8 b x ~100 cyc ~= the measured 13.5k cyc/wave/t.
// Now: pop 4 bits, issue 4 ds_read_b128, consume 4 in ascending-bit order
// (same add order -> bit-exact), uniform tail loop. Stall/bit ~4x lower.

#define BB 65536
#define TT 24
#define NB 8  // batch elements per wave (two halves of 4)

__device__ __forceinline__ float bcastf(float v, int l) {
  return __int_as_float(__builtin_amdgcn_readlane(__float_as_int(v), l));
}
__device__ __forceinline__ float sigm(float v) { return 1.0f / (1.0f + expf(-v)); }
__device__ __forceinline__ float wsum(float v) {
#pragma unroll
  for (int o = 32; o > 0; o >>= 1) v += __shfl_xor(v, o);
  return v;
}

__global__ __attribute__((amdgpu_waves_per_eu(4, 4))) __launch_bounds__(512)
void snn_pass1(
    const float* __restrict__ x, const float* __restrict__ Wih1,
    const float* __restrict__ Whh1, const float* __restrict__ bih1,
    const float* __restrict__ bhh1, const float* __restrict__ thr1p,
    unsigned long long* __restrict__ spk_out, float* __restrict__ mem1_out) {
  // P1[m][j] = {Whh1[j][m], Whh1[64+j][m], Whh1[128+j][m], Whh1[192+j][m]}
  __shared__ float4 P1[64][64];     // 64 KB
  __shared__ float stM[8][64][NB];  // 16 KB: per-wave state broadcast strip
  int tid = threadIdx.x;
  for (int idx = tid; idx < 16384; idx += 512) {
    int k = idx >> 6, m = idx & 63;
    ((float*)&P1[m][k & 63])[k >> 6] = Whh1[idx];
  }
  __syncthreads();
  int lane = tid & 63, wave = tid >> 6;
  int wb = (blockIdx.x * 8 + wave) * NB;  // first batch of this wave
  float thr1 = thr1p[0];
  float b1q[4], wq[4];
#pragma unroll
  for (int q = 0; q < 4; q++) {
    b1q[q] = bih1[q * 64 + lane] + bhh1[q * 64 + lane];
    wq[q] = Wih1[q * 64 + lane];
  }
  float syn[NB], mem[NB];
#pragma unroll
  for (int b = 0; b < NB; b++) { syn[b] = 0.0f; mem[b] = 0.0f; }

  for (int t = 0; t < TT; t++) {
    // stage this wave's OLD mem state for both halves before any update
#pragma unroll
    for (int b = 0; b < NB; b++) stM[wave][lane][b] = mem[b];
    unsigned long long myspk = 0;  // lane b keeps batch b's ballot
#pragma unroll
    for (int h = 0; h < 2; h++) {
      const int B0 = h * 4;
      float acc[4][4];
#pragma unroll
      for (int j = 0; j < 4; j++) {
        float xbt = x[(wb + B0 + j) * TT + t];
#pragma unroll
        for (int q = 0; q < 4; q++) acc[j][q] = fmaf(xbt, wq[q], b1q[q]);
      }
#pragma unroll 8
      for (int m = 0; m < 64; m++) {
        float4 w = P1[m][lane];                          // per-lane ds_read_b128
        float4 sa = *(const float4*)&stM[wave][m][B0];   // broadcast (uniform addr)
        float s[4] = {sa.x, sa.y, sa.z, sa.w};
#pragma unroll
        for (int j = 0; j < 4; j++) {
          acc[j][0] = fmaf(s[j], w.x, acc[j][0]);
          acc[j][1] = fmaf(s[j], w.y, acc[j][1]);
          acc[j][2] = fmaf(s[j], w.z, acc[j][2]);
          acc[j][3] = fmaf(s[j], w.w, acc[j][3]);
        }
      }
#pragma unroll
      for (int j = 0; j < 4; j++) {
        int b = B0 + j;
        float ig = sigm(acc[j][0]), fg = sigm(acc[j][1]);
        float gg = tanhf(acc[j][2]), og = sigm(acc[j][3]);
        float sn = fmaf(fg, syn[b], ig * gg);
        float rst = (mem[b] > thr1) ? thr1 : 0.0f;  // reset uses OLD mem
        float mn = fmaf(og, tanhf(sn), -rst);
        syn[b] = sn;
        mem[b] = mn;
        unsigned long long msk = __ballot(mn > thr1);  // wave-uniform
        if (lane == b) myspk = msk;
      }
      __builtin_amdgcn_sched_barrier(0);  // keep halves separate (live-set cap)
    }
    if (lane < NB)
      spk_out[(size_t)t * BB + wb + lane] = myspk;
  }
#pragma unroll
  for (int b = 0; b < NB; b++)
    mem1_out[(size_t)(wb + b) * 64 + lane] = mem[b];
}

__global__ __attribute__((amdgpu_waves_per_eu(4, 4))) __launch_bounds__(1024)
void snn_pass2(
    const float* __restrict__ Wih2, const float* __restrict__ Whh2,
    const float* __restrict__ bih2, const float* __restrict__ bhh2,
    const float* __restrict__ thr2p, const float* __restrict__ Wout,
    const float* __restrict__ bout,
    const unsigned long long* __restrict__ spk_in,
    const float* __restrict__ mem1_in, float* __restrict__ out) {
  __shared__ float4 Pih[64][64];     // 64 KB
  __shared__ float4 Phh[64][64];     // 64 KB
  __shared__ float stM[16][64][NB];  // 32 KB -> 160 KB total (1 block/CU)
  int tid = threadIdx.x;
  for (int idx = tid; idx < 16384; idx += 1024) {
    int k = idx >> 6, m = idx & 63;
    ((float*)&Pih[m][k & 63])[k >> 6] = Wih2[idx];
    ((float*)&Phh[m][k & 63])[k >> 6] = Whh2[idx];
  }
  __syncthreads();
  int lane = tid & 63, wave = tid >> 6;
  int wb = (blockIdx.x * 16 + wave) * NB;
  float thr2 = thr2p[0];
  float b2q[4];
#pragma unroll
  for (int q = 0; q < 4; q++) b2q[q] = bih2[q * 64 + lane] + bhh2[q * 64 + lane];
  float syn[NB], mem[NB];
  unsigned sb8[NB];  // per-lane spike history of THIS lane's neuron, bit t
#pragma unroll
  for (int b = 0; b < NB; b++) { syn[b] = 0.0f; mem[b] = 0.0f; sb8[b] = 0u; }

  for (int t = 0; t < TT; t++) {
    // spike masks -> SGPR u64 (wave-uniform)
    unsigned long long mk[NB];
#pragma unroll
    for (int b = 0; b < NB; b++) {
      unsigned long long v = spk_in[(size_t)t * BB + wb + b];
      unsigned lo = __builtin_amdgcn_readfirstlane((unsigned)v);
      unsigned hi = __builtin_amdgcn_readfirstlane((unsigned)(v >> 32));
      mk[b] = ((unsigned long long)hi << 32) | (unsigned long long)lo;
    }
    // stage OLD mem state for both halves
#pragma unroll
    for (int b = 0; b < NB; b++) stM[wave][lane][b] = mem[b];
#pragma unroll
    for (int h = 0; h < 2; h++) {
      const int B0 = h * 4;
      float acc[4][4];
#pragma unroll
      for (int j = 0; j < 4; j++) {
#pragma unroll
        for (int q = 0; q < 4; q++) acc[j][q] = b2q[q];
      }
      // dense hh half (mem is dense)
#pragma unroll 4
      for (int m = 0; m < 64; m++) {
        float4 wh = Phh[m][lane];
        float4 sa = *(const float4*)&stM[wave][m][B0];  // broadcast read
        float s[4] = {sa.x, sa.y, sa.z, sa.w};
#pragma unroll
        for (int j = 0; j < 4; j++) {
          acc[j][0] = fmaf(s[j], wh.x, acc[j][0]);
          acc[j][1] = fmaf(s[j], wh.y, acc[j][1]);
          acc[j][2] = fmaf(s[j], wh.z, acc[j][2]);
          acc[j][3] = fmaf(s[j], wh.w, acc[j][3]);
        }
      }
      // sparse ih half: 4-deep read pipeline, adds in ascending bit order
      // (same order as R9/R10 -> bit-exact). Wave-uniform control (SGPR mask).
#pragma unroll
      for (int j = 0; j < 4; j++) {
        int b = B0 + j;
        unsigned long long k = mk[b];
        while (__builtin_popcountll(k) >= 4) {
          int m0 = __builtin_ctzll(k); k &= k - 1;
          int m1 = __builtin_ctzll(k); k &= k - 1;
          int m2 = __builtin_ctzll(k); k &= k - 1;
          int m3 = __builtin_ctzll(k); k &= k - 1;
          float4 r0 = Pih[m0][lane];
          float4 r1 = Pih[m1][lane];
          float4 r2 = Pih[m2][lane];
          float4 r3 = Pih[m3][lane];  // 4 reads in flight before first consume
          acc[j][0] += r0.x; acc[j][1] += r0.y; acc[j][2] += r0.z; acc[j][3] += r0.w;
          acc[j][0] += r1.x; acc[j][1] += r1.y; acc[j][2] += r1.z; acc[j][3] += r1.w;
          acc[j][0] += r2.x; acc[j][1] += r2.y; acc[j][2] += r2.z; acc[j][3] += r2.w;
          acc[j][0] += r3.x; acc[j][1] += r3.y; acc[j][2] += r3.z; acc[j][3] += r3.w;
        }
        while (k) {
          int m0 = __builtin_ctzll(k); k &= k - 1;
          float4 r0 = Pih[m0][lane];
          acc[j][0] += r0.x; acc[j][1] += r0.y; acc[j][2] += r0.z; acc[j][3] += r0.w;
        }
        float ig = sigm(acc[j][0]), fg = sigm(acc[j][1]);
        float gg = tanhf(acc[j][2]), og = sigm(acc[j][3]);
        float sn = fmaf(fg, syn[b], ig * gg);
        float rst = (mem[b] > thr2) ? thr2 : 0.0f;
        float mn = fmaf(og, tanhf(sn), -rst);
        syn[b] = sn;
        mem[b] = mn;
        sb8[b] |= (mn > thr2) ? (1u << t) : 0u;
      }
      __builtin_amdgcn_sched_barrier(0);  // keep halves separate (live-set cap)
    }
  }

  // extra step: input = final mem1 (dense). Keeps readlane form (4% of work).
  float m1[NB];
#pragma unroll
  for (int b = 0; b < NB; b++) m1[b] = mem1_in[(size_t)(wb + b) * 64 + lane];
  float acc[NB][4];
#pragma unroll
  for (int b = 0; b < NB; b++) {
#pragma unroll
    for (int q = 0; q < 4; q++) acc[b][q] = b2q[q];
  }
#pragma unroll 4
  for (int m = 0; m < 64; m++) {
    float4 wi = Pih[m][lane];
    float4 wh = Phh[m][lane];
#pragma unroll
    for (int b = 0; b < NB; b++) {
      float s1 = bcastf(m1[b], m);
      float s2 = bcastf(mem[b], m);
      acc[b][0] = fmaf(s1, wi.x, fmaf(s2, wh.x, acc[b][0]));
      acc[b][1] = fmaf(s1, wi.y, fmaf(s2, wh.y, acc[b][1]));
      acc[b][2] = fmaf(s1, wi.z, fmaf(s2, wh.z, acc[b][2]));
      acc[b][3] = fmaf(s1, wi.w, fmaf(s2, wh.w, acc[b][3]));
    }
  }
  // epilogue: replay p0/p1 accumulation (same fmaf order as before) from bits.
  float p0[NB], p1[NB];
#pragma unroll
  for (int b = 0; b < NB; b++) { p0[b] = 0.0f; p1[b] = 0.0f; }
#pragma unroll 4
  for (int t = 0; t < TT; t++) {
    float w0 = Wout[t * 64 + lane];
    float w1 = Wout[1664 + t * 64 + lane];
#pragma unroll
    for (int b = 0; b < NB; b++) {
      float sf = ((sb8[b] >> t) & 1u) ? 1.0f : 0.0f;
      p0[b] = fmaf(sf, w0, p0[b]);
      p1[b] = fmaf(sf, w1, p1[b]);
    }
  }
  float wA0 = Wout[1536 + lane], wA1 = Wout[1664 + 1536 + lane];  // spk2_last
  float wB0 = Wout[1600 + lane], wB1 = Wout[1664 + 1600 + lane];  // mem2 final
  float bo0 = bout[0], bo1 = bout[1];
#pragma unroll
  for (int b = 0; b < NB; b++) {
    float ig = sigm(acc[b][0]), fg = sigm(acc[b][1]);
    float gg = tanhf(acc[b][2]), og = sigm(acc[b][3]);
    float sn = fmaf(fg, syn[b], ig * gg);
    float rst = (mem[b] > thr2) ? thr2 : 0.0f;
    float mn = fmaf(og, tanhf(sn), -rst);
    float sf = (mn > thr2) ? 1.0f : 0.0f;
    p0[b] = fmaf(sf, wA0, p0[b]);
    p1[b] = fmaf(sf, wA1, p1[b]);
    p0[b] = fmaf(mn, wB0, p0[b]);
    p1[b] = fmaf(mn, wB1, p1[b]);
  }
  // cross-lane reduce; wsum result is uniform, keep own lane's value.
  float vout = 0.0f;
#pragma unroll
  for (int b = 0; b < NB; b++) {
    float r0 = wsum(p0[b]);
    float r1 = wsum(p1[b]);
    if (lane == 2 * b) vout = r0;
    if (lane == 2 * b + 1) vout = r1;
  }
  if (lane < 2 * NB)
    out[(size_t)wb * 2 + lane] = vout + ((lane & 1) ? bo1 : bo0);
}

extern "C" void kernel_launch(void* const* d_in, const int* in_sizes, int n_in,
                              void* d_out, int out_size, void* d_ws, size_t ws_size,
                              hipStream_t stream) {
  const float* x = (const float*)d_in[0];
  const float* Wih1 = (const float*)d_in[1];
  const float* Whh1 = (const float*)d_in[2];
  const float* bih1 = (const float*)d_in[3];
  const float* bhh1 = (const float*)d_in[4];
  const float* thr1 = (const float*)d_in[5];
  const float* Wih2 = (const float*)d_in[6];
  const float* Whh2 = (const float*)d_in[7];
  const float* bih2 = (const float*)d_in[8];
  const float* bhh2 = (const float*)d_in[9];
  const float* thr2 = (const float*)d_in[10];
  const float* Wout = (const float*)d_in[11];
  const float* bout = (const float*)d_in[12];

  unsigned long long* spk = (unsigned long long*)d_ws;
  float* mem1 = (float*)((char*)d_ws + (size_t)TT * BB * 8);

  snn_pass1<<<BB / (8 * NB), 512, 0, stream>>>(x, Wih1, Whh1, bih1, bhh1, thr1,
                                               spk, mem1);
  snn_pass2<<<BB / (16 * NB), 1024, 0, stream>>>(Wih2, Whh2, bih2, bhh2, thr2,
                                                 Wout, bout, spk, mem1,
                                                 (float*)d_out);
}

// Round 12
// 1755.851 us; speedup vs baseline: 1.0386x; 1.0386x over previous
//
#include <hip/hip_runtime.h>
#include <cstdint>
#include <cstddef>

// SNN_53618371723788: 2-layer SLSTM, B=65536, T=24, H=64, fp32.
// Pass 1: layer-1 recurrence, emits spike bitmasks + final mem1 to d_ws.
// Pass 2: layer-2 recurrence (sparse ih via spike masks) + extra step + Wout.
//
// R12: fast activations. The persistent ~2x gap vs the FMA floor (invariant
// across VGPR/TLP/scheduling changes R9-R11) was libm expf/tanhf: ~25-35
// VALU each, 48 calls/wave/t ~= 2400-3000 cyc -- same order as the 4096-cyc
// dense FMA block. Replace with v_exp_f32/v_rcp_f32 paths (__expf,
// __fdividef): sigmoid = rcp(1+exp(-x)), tanh = 1-2*rcp(exp(2x)+1), ~5
// instr each, correct +-inf saturation. ~1e-7 relative gate error -- same
// class as R9's reorder (passed absmax 0.0), inside the spike margin.

#define BB 65536
#define TT 24
#define NB 8  // batch elements per wave (two halves of 4)

__device__ __forceinline__ float bcastf(float v, int l) {
  return __int_as_float(__builtin_amdgcn_readlane(__float_as_int(v), l));
}
__device__ __forceinline__ float sigm(float v) {
  return __fdividef(1.0f, 1.0f + __expf(-v));  // v_exp + v_rcp path
}
__device__ __forceinline__ float tanh_fast(float v) {
  // tanh(x) = 1 - 2/(e^{2x}+1); e^inf->inf, rcp(inf)->0 => saturates to +-1
  return fmaf(-2.0f, __fdividef(1.0f, __expf(2.0f * v) + 1.0f), 1.0f);
}
__device__ __forceinline__ float wsum(float v) {
#pragma unroll
  for (int o = 32; o > 0; o >>= 1) v += __shfl_xor(v, o);
  return v;
}

__global__ __attribute__((amdgpu_waves_per_eu(4, 4))) __launch_bounds__(512)
void snn_pass1(
    const float* __restrict__ x, const float* __restrict__ Wih1,
    const float* __restrict__ Whh1, const float* __restrict__ bih1,
    const float* __restrict__ bhh1, const float* __restrict__ thr1p,
    unsigned long long* __restrict__ spk_out, float* __restrict__ mem1_out) {
  // P1[m][j] = {Whh1[j][m], Whh1[64+j][m], Whh1[128+j][m], Whh1[192+j][m]}
  __shared__ float4 P1[64][64];     // 64 KB
  __shared__ float stM[8][64][NB];  // 16 KB: per-wave state broadcast strip
  int tid = threadIdx.x;
  for (int idx = tid; idx < 16384; idx += 512) {
    int k = idx >> 6, m = idx & 63;
    ((float*)&P1[m][k & 63])[k >> 6] = Whh1[idx];
  }
  __syncthreads();
  int lane = tid & 63, wave = tid >> 6;
  int wb = (blockIdx.x * 8 + wave) * NB;  // first batch of this wave
  float thr1 = thr1p[0];
  float b1q[4], wq[4];
#pragma unroll
  for (int q = 0; q < 4; q++) {
    b1q[q] = bih1[q * 64 + lane] + bhh1[q * 64 + lane];
    wq[q] = Wih1[q * 64 + lane];
  }
  float syn[NB], mem[NB];
#pragma unroll
  for (int b = 0; b < NB; b++) { syn[b] = 0.0f; mem[b] = 0.0f; }

  for (int t = 0; t < TT; t++) {
    // stage this wave's OLD mem state for both halves before any update
#pragma unroll
    for (int b = 0; b < NB; b++) stM[wave][lane][b] = mem[b];
    unsigned long long myspk = 0;  // lane b keeps batch b's ballot
#pragma unroll
    for (int h = 0; h < 2; h++) {
      const int B0 = h * 4;
      float acc[4][4];
#pragma unroll
      for (int j = 0; j < 4; j++) {
        float xbt = x[(wb + B0 + j) * TT + t];
#pragma unroll
        for (int q = 0; q < 4; q++) acc[j][q] = fmaf(xbt, wq[q], b1q[q]);
      }
#pragma unroll 8
      for (int m = 0; m < 64; m++) {
        float4 w = P1[m][lane];                          // per-lane ds_read_b128
        float4 sa = *(const float4*)&stM[wave][m][B0];   // broadcast (uniform addr)
        float s[4] = {sa.x, sa.y, sa.z, sa.w};
#pragma unroll
        for (int j = 0; j < 4; j++) {
          acc[j][0] = fmaf(s[j], w.x, acc[j][0]);
          acc[j][1] = fmaf(s[j], w.y, acc[j][1]);
          acc[j][2] = fmaf(s[j], w.z, acc[j][2]);
          acc[j][3] = fmaf(s[j], w.w, acc[j][3]);
        }
      }
#pragma unroll
      for (int j = 0; j < 4; j++) {
        int b = B0 + j;
        float ig = sigm(acc[j][0]), fg = sigm(acc[j][1]);
        float gg = tanh_fast(acc[j][2]), og = sigm(acc[j][3]);
        float sn = fmaf(fg, syn[b], ig * gg);
        float rst = (mem[b] > thr1) ? thr1 : 0.0f;  // reset uses OLD mem
        float mn = fmaf(og, tanh_fast(sn), -rst);
        syn[b] = sn;
        mem[b] = mn;
        unsigned long long msk = __ballot(mn > thr1);  // wave-uniform
        if (lane == b) myspk = msk;
      }
      __builtin_amdgcn_sched_barrier(0);  // keep halves separate (live-set cap)
    }
    if (lane < NB)
      spk_out[(size_t)t * BB + wb + lane] = myspk;
  }
#pragma unroll
  for (int b = 0; b < NB; b++)
    mem1_out[(size_t)(wb + b) * 64 + lane] = mem[b];
}

__global__ __attribute__((amdgpu_waves_per_eu(4, 4))) __launch_bounds__(1024)
void snn_pass2(
    const float* __restrict__ Wih2, const float* __restrict__ Whh2,
    const float* __restrict__ bih2, const float* __restrict__ bhh2,
    const float* __restrict__ thr2p, const float* __restrict__ Wout,
    const float* __restrict__ bout,
    const unsigned long long* __restrict__ spk_in,
    const float* __restrict__ mem1_in, float* __restrict__ out) {
  __shared__ float4 Pih[64][64];     // 64 KB
  __shared__ float4 Phh[64][64];     // 64 KB
  __shared__ float stM[16][64][NB];  // 32 KB -> 160 KB total (1 block/CU)
  int tid = threadIdx.x;
  for (int idx = tid; idx < 16384; idx += 1024) {
    int k = idx >> 6, m = idx & 63;
    ((float*)&Pih[m][k & 63])[k >> 6] = Wih2[idx];
    ((float*)&Phh[m][k & 63])[k >> 6] = Whh2[idx];
  }
  __syncthreads();
  int lane = tid & 63, wave = tid >> 6;
  int wb = (blockIdx.x * 16 + wave) * NB;
  float thr2 = thr2p[0];
  float b2q[4];
#pragma unroll
  for (int q = 0; q < 4; q++) b2q[q] = bih2[q * 64 + lane] + bhh2[q * 64 + lane];
  float syn[NB], mem[NB];
  unsigned sb8[NB];  // per-lane spike history of THIS lane's neuron, bit t
#pragma unroll
  for (int b = 0; b < NB; b++) { syn[b] = 0.0f; mem[b] = 0.0f; sb8[b] = 0u; }

  for (int t = 0; t < TT; t++) {
    // spike masks -> SGPR u64 (wave-uniform)
    unsigned long long mk[NB];
#pragma unroll
    for (int b = 0; b < NB; b++) {
      unsigned long long v = spk_in[(size_t)t * BB + wb + b];
      unsigned lo = __builtin_amdgcn_readfirstlane((unsigned)v);
      unsigned hi = __builtin_amdgcn_readfirstlane((unsigned)(v >> 32));
      mk[b] = ((unsigned long long)hi << 32) | (unsigned long long)lo;
    }
    // stage OLD mem state for both halves
#pragma unroll
    for (int b = 0; b < NB; b++) stM[wave][lane][b] = mem[b];
#pragma unroll
    for (int h = 0; h < 2; h++) {
      const int B0 = h * 4;
      float acc[4][4];
#pragma unroll
      for (int j = 0; j < 4; j++) {
#pragma unroll
        for (int q = 0; q < 4; q++) acc[j][q] = b2q[q];
      }
      // dense hh half (mem is dense)
#pragma unroll 4
      for (int m = 0; m < 64; m++) {
        float4 wh = Phh[m][lane];
        float4 sa = *(const float4*)&stM[wave][m][B0];  // broadcast read
        float s[4] = {sa.x, sa.y, sa.z, sa.w};
#pragma unroll
        for (int j = 0; j < 4; j++) {
          acc[j][0] = fmaf(s[j], wh.x, acc[j][0]);
          acc[j][1] = fmaf(s[j], wh.y, acc[j][1]);
          acc[j][2] = fmaf(s[j], wh.z, acc[j][2]);
          acc[j][3] = fmaf(s[j], wh.w, acc[j][3]);
        }
      }
      // sparse ih half: 4-deep read pipeline, adds in ascending bit order.
#pragma unroll
      for (int j = 0; j < 4; j++) {
        int b = B0 + j;
        unsigned long long k = mk[b];
        while (__builtin_popcountll(k) >= 4) {
          int m0 = __builtin_ctzll(k); k &= k - 1;
          int m1 = __builtin_ctzll(k); k &= k - 1;
          int m2 = __builtin_ctzll(k); k &= k - 1;
          int m3 = __builtin_ctzll(k); k &= k - 1;
          float4 r0 = Pih[m0][lane];
          float4 r1 = Pih[m1][lane];
          float4 r2 = Pih[m2][lane];
          float4 r3 = Pih[m3][lane];  // 4 reads in flight before first consume
          acc[j][0] += r0.x; acc[j][1] += r0.y; acc[j][2] += r0.z; acc[j][3] += r0.w;
          acc[j][0] += r1.x; acc[j][1] += r1.y; acc[j][2] += r1.z; acc[j][3] += r1.w;
          acc[j][0] += r2.x; acc[j][1] += r2.y; acc[j][2] += r2.z; acc[j][3] += r2.w;
          acc[j][0] += r3.x; acc[j][1] += r3.y; acc[j][2] += r3.z; acc[j][3] += r3.w;
        }
        while (k) {
          int m0 = __builtin_ctzll(k); k &= k - 1;
          float4 r0 = Pih[m0][lane];
          acc[j][0] += r0.x; acc[j][1] += r0.y; acc[j][2] += r0.z; acc[j][3] += r0.w;
        }
        float ig = sigm(acc[j][0]), fg = sigm(acc[j][1]);
        float gg = tanh_fast(acc[j][2]), og = sigm(acc[j][3]);
        float sn = fmaf(fg, syn[b], ig * gg);
        float rst = (mem[b] > thr2) ? thr2 : 0.0f;
        float mn = fmaf(og, tanh_fast(sn), -rst);
        syn[b] = sn;
        mem[b] = mn;
        sb8[b] |= (mn > thr2) ? (1u << t) : 0u;
      }
      __builtin_amdgcn_sched_barrier(0);  // keep halves separate (live-set cap)
    }
  }

  // extra step: input = final mem1 (dense). Keeps readlane form (4% of work).
  float m1[NB];
#pragma unroll
  for (int b = 0; b < NB; b++) m1[b] = mem1_in[(size_t)(wb + b) * 64 + lane];
  float acc[NB][4];
#pragma unroll
  for (int b = 0; b < NB; b++) {
#pragma unroll
    for (int q = 0; q < 4; q++) acc[b][q] = b2q[q];
  }
#pragma unroll 4
  for (int m = 0; m < 64; m++) {
    float4 wi = Pih[m][lane];
    float4 wh = Phh[m][lane];
#pragma unroll
    for (int b = 0; b < NB; b++) {
      float s1 = bcastf(m1[b], m);
      float s2 = bcastf(mem[b], m);
      acc[b][0] = fmaf(s1, wi.x, fmaf(s2, wh.x, acc[b][0]));
      acc[b][1] = fmaf(s1, wi.y, fmaf(s2, wh.y, acc[b][1]));
      acc[b][2] = fmaf(s1, wi.z, fmaf(s2, wh.z, acc[b][2]));
      acc[b][3] = fmaf(s1, wi.w, fmaf(s2, wh.w, acc[b][3]));
    }
  }
  // epilogue: replay p0/p1 accumulation (same fmaf order as before) from bits.
  float p0[NB], p1[NB];
#pragma unroll
  for (int b = 0; b < NB; b++) { p0[b] = 0.0f; p1[b] = 0.0f; }
#pragma unroll 4
  for (int t = 0; t < TT; t++) {
    float w0 = Wout[t * 64 + lane];
    float w1 = Wout[1664 + t * 64 + lane];
#pragma unroll
    for (int b = 0; b < NB; b++) {
      float sf = ((sb8[b] >> t) & 1u) ? 1.0f : 0.0f;
      p0[b] = fmaf(sf, w0, p0[b]);
      p1[b] = fmaf(sf, w1, p1[b]);
    }
  }
  float wA0 = Wout[1536 + lane], wA1 = Wout[1664 + 1536 + lane];  // spk2_last
  float wB0 = Wout[1600 + lane], wB1 = Wout[1664 + 1600 + lane];  // mem2 final
  float bo0 = bout[0], bo1 = bout[1];
#pragma unroll
  for (int b = 0; b < NB; b++) {
    float ig = sigm(acc[b][0]), fg = sigm(acc[b][1]);
    float gg = tanh_fast(acc[b][2]), og = sigm(acc[b][3]);
    float sn = fmaf(fg, syn[b], ig * gg);
    float rst = (mem[b] > thr2) ? thr2 : 0.0f;
    float mn = fmaf(og, tanh_fast(sn), -rst);
    float sf = (mn > thr2) ? 1.0f : 0.0f;
    p0[b] = fmaf(sf, wA0, p0[b]);
    p1[b] = fmaf(sf, wA1, p1[b]);
    p0[b] = fmaf(mn, wB0, p0[b]);
    p1[b] = fmaf(mn, wB1, p1[b]);
  }
  // cross-lane reduce; wsum result is uniform, keep own lane's value.
  float vout = 0.0f;
#pragma unroll
  for (int b = 0; b < NB; b++) {
    float r0 = wsum(p0[b]);
    float r1 = wsum(p1[b]);
    if (lane == 2 * b) vout = r0;
    if (lane == 2 * b + 1) vout = r1;
  }
  if (lane < 2 * NB)
    out[(size_t)wb * 2 + lane] = vout + ((lane & 1) ? bo1 : bo0);
}

extern "C" void kernel_launch(void* const* d_in, const int* in_sizes, int n_in,
                              void* d_out, int out_size, void* d_ws, size_t ws_size,
                              hipStream_t stream) {
  const float* x = (const float*)d_in[0];
  const float* Wih1 = (const float*)d_in[1];
  const float* Whh1 = (const float*)d_in[2];
  const float* bih1 = (const float*)d_in[3];
  const float* bhh1 = (const float*)d_in[4];
  const float* thr1 = (const float*)d_in[5];
  const float* Wih2 = (const float*)d_in[6];
  const float* Whh2 = (const float*)d_in[7];
  const float* bih2 = (const float*)d_in[8];
  const float* bhh2 = (const float*)d_in[9];
  const float* thr2 = (const float*)d_in[10];
  const float* Wout = (const float*)d_in[11];
  const float* bout = (const float*)d_in[12];

  unsigned long long* spk = (unsigned long long*)d_ws;
  float* mem1 = (float*)((char*)d_ws + (size_t)TT * BB * 8);

  snn_pass1<<<BB / (8 * NB), 512, 0, stream>>>(x, Wih1, Whh1, bih1, bhh1, thr1,
                                               spk, mem1);
  snn_pass2<<<BB / (16 * NB), 1024, 0, stream>>>(Wih2, Whh2, bih2, bhh2, thr2,
                                                 Wout, bout, spk, mem1,
                                                 (float*)d_out);
}